// Round 4
// baseline (60.465 us; speedup 1.0000x reference)
//
#include <hip/hip_runtime.h>

// OpponentModelOracle: B=512, H=128, W=128, C=4 one-hot f32 input.
// Output: tuple (g_map [B,H,W] f32 with a single 1.0 per batch iff food exists,
//                zeros [B,H,W] f32), concatenated flat in d_out.
//
// R3: split into a pure-read scan kernel (target index per batch -> d_ws)
// and a pure-write fill kernel (zeros + merged 1.0). Rationale: harness fill
// kernels sustain 7.0-7.15 TB/s write-only vs our 5.9 TB/s mixed stream.
// NT stores reverted (R2: -5.6%).

#define HW_CELLS 16384   // 128*128
#define W_DIM    128
#define B_DIM    512

// ---------------- Kernel A: pure-read scan, one block per batch ----------------
__global__ __launch_bounds__(512)
void scan_kernel(const float4* __restrict__ x, unsigned* __restrict__ tgt) {
    const int b   = blockIdx.x;
    const int tid = threadIdx.x;

    __shared__ unsigned int foodmask[HW_CELLS / 32];  // 512 words, 2 KB
    __shared__ unsigned int opp_min;                   // first opponent flat idx
    __shared__ unsigned int key_min;                   // (sqdist<<14)|idx
    __shared__ unsigned int food_cnt;

    foodmask[tid] = 0u;  // blockDim.x == 512 == number of words
    if (tid == 0) {
        opp_min  = 0xFFFFFFFFu;
        key_min  = 0xFFFFFFFFu;
        food_cnt = 0u;
    }
    __syncthreads();

    const float4* xb = x + (size_t)b * HW_CELLS;

    // Coalesced 16B/lane scan: food bitmap + first opponent index.
    for (int i = 0; i < HW_CELLS / 512; ++i) {
        const int cell = tid + i * 512;
        const float4 v = xb[cell];
        if (v.y == 1.0f) atomicOr(&foodmask[cell >> 5], 1u << (cell & 31));
        if (v.w == 1.0f) atomicMin(&opp_min, (unsigned)cell);
    }
    __syncthreads();

    // First opponent (argmax over booleans: 0 if none) -> coords.
    unsigned opp = opp_min;
    if (opp == 0xFFFFFFFFu) opp = 0u;
    const int opp_r = (int)(opp >> 7);
    const int opp_c = (int)(opp & (W_DIM - 1));

    // Each thread owns one bitmap word; popcount + per-food-cell min key.
    unsigned m   = foodmask[tid];
    const int cnt = __popc(m);
    unsigned local_key = 0xFFFFFFFFu;
    while (m) {
        const int bit = __ffs(m) - 1;
        m &= m - 1u;
        const int idx = (tid << 5) | bit;
        const int r = idx >> 7;
        const int c = idx & (W_DIM - 1);
        const int dr = r - opp_r;
        const int dc = c - opp_c;
        const unsigned sq = (unsigned)(dr * dr + dc * dc);   // <= 32258 < 2^15
        const unsigned key = (sq << 14) | (unsigned)idx;     // idx < 2^14
        if (key < local_key) local_key = key;
    }
    if (local_key != 0xFFFFFFFFu) atomicMin(&key_min, local_key);
    if (cnt) atomicAdd(&food_cnt, (unsigned)cnt);

    __syncthreads();

    if (tid == 0) {
        const unsigned fc = food_cnt;
        unsigned t = 0xFFFFFFFFu;                    // no food: no 1.0 write
        if (fc > 0u) {
            const unsigned min_idx = key_min & 16383u;
            const bool opp_at_start = (opp_r == 3) && (opp_c == 6);
            const bool use_min = (fc == 1u) || (fc > 1u && !opp_at_start);
            t = use_min ? min_idx : 0u;
        }
        tgt[b] = t;
    }
}

// ---------------- Kernel B: pure-write fill (zeros + merged 1.0) ----------------
// d_out viewed as 4,194,304 float4s: first 2,097,152 = g_map, rest = zeros map.
__global__ __launch_bounds__(256)
void fill_kernel(float4* __restrict__ out, const unsigned* __restrict__ tgt) {
    const int f = blockIdx.x * 256 + threadIdx.x;   // 4096 blocks * 256 thr
    #pragma unroll
    for (int i = 0; i < 4; ++i) {
        const int idx = f + i * (4096 * 256);       // [0, 4194304)
        float4 v = make_float4(0.f, 0.f, 0.f, 0.f);
        if (i < 2) {                                 // g_map half only
            const unsigned b = (unsigned)idx >> 12;  // 4096 float4 per batch map
            const unsigned t = tgt[b];               // L2-broadcast, 2 KB table
            if ((t >> 2) == ((unsigned)idx & 4095u)) {
                reinterpret_cast<float*>(&v)[t & 3u] = 1.0f;
            }
        }
        out[idx] = v;
    }
}

extern "C" void kernel_launch(void* const* d_in, const int* in_sizes, int n_in,
                              void* d_out, int out_size, void* d_ws, size_t ws_size,
                              hipStream_t stream) {
    const float4* x = (const float4*)d_in[0];
    float4* out = (float4*)d_out;
    unsigned* tgt = (unsigned*)d_ws;                 // 512 * 4 B scratch

    scan_kernel<<<B_DIM, 512, 0, stream>>>(x, tgt);
    fill_kernel<<<4096, 256, 0, stream>>>(out, tgt);
}

// Round 5
// 34.071 us; speedup vs baseline: 1.7747x; 1.7747x over previous
//
#include <hip/hip_runtime.h>

// OpponentModelOracle: B=512, H=128, W=128, C=4 one-hot f32 input.
// Output: tuple (g_map [B,H,W] f32 with a single 1.0 per batch iff food exists,
//                zeros [B,H,W] f32), concatenated flat in d_out.
//
// R4: revert to the round-1 winner (34.07 us, 94% of the 6.29 TB/s mixed-stream
// ceiling on 201.3 MB mandatory traffic). Rejected experiments:
//   - R2 nontemporal zero-stores: 36.0 us (-5.6%) — L3-residency theory dead.
//   - R3 read/write kernel split: 60.5 us (-77%) — mixed stream beats
//     serialized unidirectional phases; concurrent read+write bus use is
//     exactly what the fused kernel already gets.

#define HW_CELLS 16384   // 128*128
#define W_DIM    128

__global__ __launch_bounds__(512)
void oracle_kernel(const float4* __restrict__ x,
                   float* __restrict__ out0,
                   float* __restrict__ out1) {
    const int b   = blockIdx.x;
    const int tid = threadIdx.x;

    __shared__ unsigned int foodmask[HW_CELLS / 32];  // 512 words, 2 KB
    __shared__ unsigned int opp_min;                   // first opponent flat idx
    __shared__ unsigned int key_min;                   // (sqdist<<14)|idx
    __shared__ unsigned int food_cnt;

    foodmask[tid] = 0u;  // blockDim.x == 512 == number of words
    if (tid == 0) {
        opp_min  = 0xFFFFFFFFu;
        key_min  = 0xFFFFFFFFu;
        food_cnt = 0u;
    }
    __syncthreads();

    const float4* xb = x + (size_t)b * HW_CELLS;

    // Phase 1: scan all cells (coalesced 16B/lane), build food bitmap + first-opp.
    for (int i = 0; i < HW_CELLS / 512; ++i) {
        const int cell = tid + i * 512;
        const float4 v = xb[cell];
        if (v.y == 1.0f) atomicOr(&foodmask[cell >> 5], 1u << (cell & 31));
        if (v.w == 1.0f) atomicMin(&opp_min, (unsigned)cell);
    }

    // Fused: zero both output maps (coalesced float4 stores).
    float4* o0 = reinterpret_cast<float4*>(out0 + (size_t)b * HW_CELLS);
    float4* o1 = reinterpret_cast<float4*>(out1 + (size_t)b * HW_CELLS);
    const float4 z = make_float4(0.f, 0.f, 0.f, 0.f);
    for (int i = 0; i < HW_CELLS / 4 / 512; ++i) {
        o0[tid + i * 512] = z;
        o1[tid + i * 512] = z;
    }

    __syncthreads();

    // First opponent (argmax over booleans: 0 if none) -> coords.
    unsigned opp = opp_min;
    if (opp == 0xFFFFFFFFu) opp = 0u;
    const int opp_r = (int)(opp >> 7);
    const int opp_c = (int)(opp & (W_DIM - 1));

    // Phase 2: each thread owns one bitmap word; popcount + per-food-cell key.
    unsigned m   = foodmask[tid];
    const int cnt = __popc(m);
    unsigned local_key = 0xFFFFFFFFu;
    while (m) {
        const int bit = __ffs(m) - 1;
        m &= m - 1u;
        const int idx = (tid << 5) | bit;
        const int r = idx >> 7;
        const int c = idx & (W_DIM - 1);
        const int dr = r - opp_r;
        const int dc = c - opp_c;
        const unsigned sq = (unsigned)(dr * dr + dc * dc);   // <= 32258 < 2^15
        const unsigned key = (sq << 14) | (unsigned)idx;     // idx < 2^14
        if (key < local_key) local_key = key;
    }
    if (local_key != 0xFFFFFFFFu) atomicMin(&key_min, local_key);
    if (cnt) atomicAdd(&food_cnt, (unsigned)cnt);

    __syncthreads();

    // Phase 3: apply placement policy, single write.
    if (tid == 0) {
        const unsigned fc = food_cnt;
        if (fc > 0u) {
            const unsigned min_idx = key_min & 16383u;
            const bool opp_at_start = (opp_r == 3) && (opp_c == 6);
            const bool use_min = (fc == 1u) || (fc > 1u && !opp_at_start);
            const unsigned tgt = use_min ? min_idx : 0u;
            out0[(size_t)b * HW_CELLS + tgt] = 1.0f;
        }
    }
}

extern "C" void kernel_launch(void* const* d_in, const int* in_sizes, int n_in,
                              void* d_out, int out_size, void* d_ws, size_t ws_size,
                              hipStream_t stream) {
    const float4* x = (const float4*)d_in[0];
    float* out = (float*)d_out;
    const int B = 512;
    float* out0 = out;                         // g_map
    float* out1 = out + (size_t)B * HW_CELLS;  // zeros_like(g_map)

    oracle_kernel<<<B, 512, 0, stream>>>(x, out0, out1);
}